// Round 1
// 464.076 us; speedup vs baseline: 1.0103x; 1.0103x over previous
//
#include <hip/hip_runtime.h>
#include <math.h>

// Problem constants (fixed by reference: x = (16, 256, 128, 128) fp32)
#define B_   16
#define C_   256
#define H_   128
#define W_   128
#define HW_  (H_ * W_)          // 16384
#define CHW_ (C_ * HW_)         // 4194304
#define NSPATIAL_ (B_ * HW_)    // 262144
#define NTOTAL_   (B_ * CHW_)   // 67108864

typedef float f4 __attribute__((ext_vector_type(4)));

// ---------------------------------------------------------------------------
// K1: per-(b,h,w) mean + max over C.
// v2: 4-way channel split across the 4 waves of a 256-thread block, LDS
// combine. Grid 256 -> 1024 blocks (1 -> 4 blocks/CU, 4 -> 16 waves/CU) to
// fix the latency-bound 1-wave/SIMD occupancy of v1.
//   thread layout: col = tid & 63 (float4 spatial column within block's 64),
//                  split = tid >> 6 == wave id (channel chunk of 64).
// Each wave's load is 64 lanes x 16 B contiguous = 1 KiB, fully coalesced.
// ---------------------------------------------------------------------------
__global__ __launch_bounds__(256) void k1_reduce(const float* __restrict__ x,
                                                 float* __restrict__ avgmap,
                                                 float* __restrict__ maxmap) {
    __shared__ float4 lsum[4][64];
    __shared__ float4 lmax[4][64];

    const int col   = threadIdx.x & 63;
    const int split = threadIdx.x >> 6;                 // 0..3, == wave id
    const int i     = blockIdx.x * 64 + col;            // float4 column [0, 65536)
    const int b     = i >> 12;                          // / (HW/4 = 4096)
    const int r     = i & 4095;
    const int cs    = HW_ / 4;                          // channel stride in float4

    const float4* p = reinterpret_cast<const float4*>(x + (size_t)b * CHW_)
                      + r + (size_t)(split * 64) * cs;  // this wave's 64-channel chunk

    // 4 independent accumulators for ILP within the 64-deep chunk.
    float4 s0 = make_float4(0.f, 0.f, 0.f, 0.f), s1 = s0, s2 = s0, s3 = s0;
    float4 m0 = make_float4(-INFINITY, -INFINITY, -INFINITY, -INFINITY);
    float4 m1 = m0, m2 = m0, m3 = m0;

    #pragma unroll 2
    for (int c = 0; c < 64; c += 4) {
        float4 a0 = p[(size_t)(c + 0) * cs];
        float4 a1 = p[(size_t)(c + 1) * cs];
        float4 a2 = p[(size_t)(c + 2) * cs];
        float4 a3 = p[(size_t)(c + 3) * cs];
        s0.x += a0.x; s0.y += a0.y; s0.z += a0.z; s0.w += a0.w;
        s1.x += a1.x; s1.y += a1.y; s1.z += a1.z; s1.w += a1.w;
        s2.x += a2.x; s2.y += a2.y; s2.z += a2.z; s2.w += a2.w;
        s3.x += a3.x; s3.y += a3.y; s3.z += a3.z; s3.w += a3.w;
        m0.x = fmaxf(m0.x, a0.x); m0.y = fmaxf(m0.y, a0.y); m0.z = fmaxf(m0.z, a0.z); m0.w = fmaxf(m0.w, a0.w);
        m1.x = fmaxf(m1.x, a1.x); m1.y = fmaxf(m1.y, a1.y); m1.z = fmaxf(m1.z, a1.z); m1.w = fmaxf(m1.w, a1.w);
        m2.x = fmaxf(m2.x, a2.x); m2.y = fmaxf(m2.y, a2.y); m2.z = fmaxf(m2.z, a2.z); m2.w = fmaxf(m2.w, a2.w);
        m3.x = fmaxf(m3.x, a3.x); m3.y = fmaxf(m3.y, a3.y); m3.z = fmaxf(m3.z, a3.z); m3.w = fmaxf(m3.w, a3.w);
    }

    float4 sum, mx;
    sum.x = (s0.x + s1.x) + (s2.x + s3.x);
    sum.y = (s0.y + s1.y) + (s2.y + s3.y);
    sum.z = (s0.z + s1.z) + (s2.z + s3.z);
    sum.w = (s0.w + s1.w) + (s2.w + s3.w);
    mx.x = fmaxf(fmaxf(m0.x, m1.x), fmaxf(m2.x, m3.x));
    mx.y = fmaxf(fmaxf(m0.y, m1.y), fmaxf(m2.y, m3.y));
    mx.z = fmaxf(fmaxf(m0.z, m1.z), fmaxf(m2.z, m3.z));
    mx.w = fmaxf(fmaxf(m0.w, m1.w), fmaxf(m2.w, m3.w));

    lsum[split][col] = sum;
    lmax[split][col] = mx;
    __syncthreads();

    if (threadIdx.x < 64) {
        const int t  = threadIdx.x;
        const int ii = blockIdx.x * 64 + t;

        float4 A0 = lsum[0][t], A1 = lsum[1][t], A2 = lsum[2][t], A3 = lsum[3][t];
        float4 M0 = lmax[0][t], M1 = lmax[1][t], M2 = lmax[2][t], M3 = lmax[3][t];

        float4 S, M;
        S.x = (A0.x + A1.x) + (A2.x + A3.x);
        S.y = (A0.y + A1.y) + (A2.y + A3.y);
        S.z = (A0.z + A1.z) + (A2.z + A3.z);
        S.w = (A0.w + A1.w) + (A2.w + A3.w);
        M.x = fmaxf(fmaxf(M0.x, M1.x), fmaxf(M2.x, M3.x));
        M.y = fmaxf(fmaxf(M0.y, M1.y), fmaxf(M2.y, M3.y));
        M.z = fmaxf(fmaxf(M0.z, M1.z), fmaxf(M2.z, M3.z));
        M.w = fmaxf(fmaxf(M0.w, M1.w), fmaxf(M2.w, M3.w));

        const float inv_c = 1.0f / (float)C_;
        float4 avg = make_float4(S.x * inv_c, S.y * inv_c, S.z * inv_c, S.w * inv_c);

        reinterpret_cast<float4*>(avgmap)[ii] = avg;
        reinterpret_cast<float4*>(maxmap)[ii] = M;
    }
}

// ---------------------------------------------------------------------------
// K2: 5-point cross stencil on avg/max maps (+zero boundary), sigmoid -> smap.
// Tiny kernel (262144 threads), maps are L2-hot. Unchanged from v1.
// ---------------------------------------------------------------------------
__global__ __launch_bounds__(256) void k2_stencil(const float* __restrict__ avgmap,
                                                  const float* __restrict__ maxmap,
                                                  const float* __restrict__ wts,
                                                  float* __restrict__ smap) {
    int tid = blockIdx.x * blockDim.x + threadIdx.x;    // [0, B*HW)
    int b  = tid >> 14;                                 // / HW
    int hw = tid & (HW_ - 1);
    int h  = hw >> 7;
    int w  = hw & (W_ - 1);

    // p[b,0,:] gates the avg map, p[b,1,:] gates the max map.
    float p0 = wts[b * 8 + 0], p1 = wts[b * 8 + 1], p2 = wts[b * 8 + 2], p3 = wts[b * 8 + 3];
    float q0 = wts[b * 8 + 4], q1 = wts[b * 8 + 5], q2 = wts[b * 8 + 6], q3 = wts[b * 8 + 7];
    float c0 = -(p0 + p1 + p2 + p3);
    float c1 = -(q0 + q1 + q2 + q3);

    int idx = b * HW_ + hw;
    float a_t = (h > 0)      ? avgmap[idx - W_] : 0.f;
    float a_b = (h < H_ - 1) ? avgmap[idx + W_] : 0.f;
    float a_l = (w > 0)      ? avgmap[idx - 1]  : 0.f;
    float a_r = (w < W_ - 1) ? avgmap[idx + 1]  : 0.f;
    float a_c = avgmap[idx];
    float m_t = (h > 0)      ? maxmap[idx - W_] : 0.f;
    float m_b = (h < H_ - 1) ? maxmap[idx + W_] : 0.f;
    float m_l = (w > 0)      ? maxmap[idx - 1]  : 0.f;
    float m_r = (w < W_ - 1) ? maxmap[idx + 1]  : 0.f;
    float m_c = maxmap[idx];

    float y3 = p0 * a_t + p1 * a_b + p2 * a_l + p3 * a_r + c0 * a_c
             + q0 * m_t + q1 * m_b + q2 * m_l + q3 * m_r + c1 * m_c;

    smap[idx] = 1.0f / (1.0f + expf(-y3));
}

// ---------------------------------------------------------------------------
// K3: out = x * s + x, with s broadcast over the channel dim. float4 streams.
// v2: nontemporal load of x and nontemporal store of out (zero reuse, don't
// pollute L1/L2/L3). smap stays cached (reused across 256 channels).
// ---------------------------------------------------------------------------
__global__ __launch_bounds__(256) void k3_apply(const float* __restrict__ x,
                                                const float* __restrict__ smap,
                                                float* __restrict__ out) {
    int i4 = blockIdx.x * blockDim.x + threadIdx.x;     // [0, NTOTAL/4)
    int b   = i4 >> 20;                                 // / (CHW/4 = 1048576)
    int hw4 = i4 & 4095;                                // float4 idx within image plane
    int sidx = b * 4096 + hw4;

    f4 xv = __builtin_nontemporal_load(reinterpret_cast<const f4*>(x) + i4);
    f4 sv = *(reinterpret_cast<const f4*>(smap) + sidx);
    f4 o;
    o.x = fmaf(xv.x, sv.x, xv.x);
    o.y = fmaf(xv.y, sv.y, xv.y);
    o.z = fmaf(xv.z, sv.z, xv.z);
    o.w = fmaf(xv.w, sv.w, xv.w);
    __builtin_nontemporal_store(o, reinterpret_cast<f4*>(out) + i4);
}

extern "C" void kernel_launch(void* const* d_in, const int* in_sizes, int n_in,
                              void* d_out, int out_size, void* d_ws, size_t ws_size,
                              hipStream_t stream) {
    const float* x   = (const float*)d_in[0];
    const float* wts = (const float*)d_in[1];
    float* out = (float*)d_out;

    // Workspace layout: avgmap | maxmap | smap, each B*HW = 262144 floats (1 MiB).
    float* avgmap = (float*)d_ws;
    float* maxmap = avgmap + NSPATIAL_;
    float* smap   = maxmap + NSPATIAL_;

    // K1: 64 float4 columns per block x 4-way C-split -> 1024 blocks.
    k1_reduce<<<(NSPATIAL_ / 4) / 64, 256, 0, stream>>>(x, avgmap, maxmap);
    // K2: one thread per spatial point -> 262144 threads.
    k2_stencil<<<NSPATIAL_ / 256, 256, 0, stream>>>(avgmap, maxmap, wts, smap);
    // K3: one thread per float4 of x -> 16777216 threads.
    k3_apply<<<(NTOTAL_ / 4) / 256, 256, 0, stream>>>(x, smap, out);
}